// Round 9
// baseline (158.336 us; speedup 1.0000x reference)
//
#include <hip/hip_runtime.h>
#include <math.h>

// CapsuleLayer: u = x@W via split-precision f16 MFMA (xh@Wh + xl@Wh + xh@Wl),
// 32x32x16, dbuf LDS staging for both operands, DPP routing epilogue.
// R9: 2 blocks/CU. R8 counters: MFMA busy == 21us floor but util 25%,
// Occupancy 20% (1 block/CU) -> per-kt barrier drains exposed (m97 plateau,
// ~900 TF effective). Fix per m114: sibling block fills the bubbles.
// Block = 256 thr (4 waves), tile 64 rows x 512 cols, grid 512.
// LDS/block: Bs[2][2][512][16] 64K + As[2][64][64B] 8K = 72K -> 2 blocks/CU.
//
// Wave w owns cols w*128..+127, all 64 rows (2 m-frags). Per kt: 1 barrier,
// 8 B-DMA + 1 A-load (stage kt+1), 12 ds_read_b128, 24 MFMA, cvt+2 ds_write.
// Epilogue: 2 phases of 32 rows via u_lds[32][520] (unions Bs), 8 rows/wave
// per phase, routing via DPP row_ror / swizzle<=31 / bpermute(32) (R7 rules:
// never runtime-index acc[] (R6 spill); lane bit 5 only via bpermute (R5)).

#define BATCH   32768
#define KDIM    512
#define NDIM    512
#define OUT_DIM 32
#define EPS_F   1e-8f
#define NKT     32            // K tiles of 16

typedef _Float16 half8  __attribute__((ext_vector_type(8)));
typedef _Float16 half4t __attribute__((ext_vector_type(4)));
typedef float   floatx4 __attribute__((ext_vector_type(4)));
typedef float  floatx16 __attribute__((ext_vector_type(16)));

// ---- cross-lane helpers (R7, proven) ----
template <int CTRL>
__device__ __forceinline__ float dpp_mov(float x) {
    return __int_as_float(__builtin_amdgcn_mov_dpp(__float_as_int(x), CTRL, 0xF, 0xF, true));
}
template <int XMASK>   // XMASK <= 31: ds_swizzle BitMode xor (within 32-lane group)
__device__ __forceinline__ float swz_xor(float x) {
    return __int_as_float(__builtin_amdgcn_ds_swizzle(__float_as_int(x), (XMASK << 10) | 31));
}
#define ROR4  0x124  // row_ror:4
#define ROR8  0x128  // row_ror:8
#define QXOR1 0xB1   // quad_perm [1,0,3,2] = xor 1
#define QXOR2 0x4E   // quad_perm [2,3,0,1] = xor 2

__device__ __forceinline__ float cap_sum(float x) {
    x += dpp_mov<ROR4>(x);
    x += dpp_mov<ROR8>(x);
    x += swz_xor<16>(x);
    x += __shfl_xor(x, 32);          // lane bit 5: bpermute only
    return x;
}
__device__ __forceinline__ float cap_max(float x) {
    x = fmaxf(x, dpp_mov<ROR4>(x));
    x = fmaxf(x, dpp_mov<ROR8>(x));
    x = fmaxf(x, swz_xor<16>(x));
    x = fmaxf(x, __shfl_xor(x, 32));
    return x;
}
__device__ __forceinline__ float dg_sum(float x) {
    x += dpp_mov<QXOR1>(x);
    x += dpp_mov<QXOR2>(x);
    return x;
}

// ---- prep: W[k][n] fp32 -> Wh/Wl [kt][n][k%16] f16 hi/lo split ----
__global__ void prep_w(const float* __restrict__ W, _Float16* __restrict__ Wh,
                       _Float16* __restrict__ Wl) {
    __shared__ float tile[32][33];
    const int tx = threadIdx.x, ty = threadIdx.y;      // block (32, 8)
    const int n0 = blockIdx.x * 32, k0 = blockIdx.y * 32;
#pragma unroll
    for (int i = 0; i < 4; ++i)
        tile[ty + 8 * i][tx] = W[(size_t)(k0 + ty + 8 * i) * NDIM + n0 + tx];
    __syncthreads();
#pragma unroll
    for (int i = 0; i < 4; ++i) {
        const int k = k0 + tx, n = n0 + ty + 8 * i;
        const float v = tile[tx][ty + 8 * i];          // = W[k][n]
        const _Float16 h = (_Float16)v;
        const _Float16 l = (_Float16)(v - (float)h);
        const size_t off = (size_t)(k >> 4) * (NDIM * 16) + (size_t)n * 16 + (k & 15);
        Wh[off] = h;
        Wl[off] = l;
    }
}

__device__ __forceinline__ void ld_g2l_16(void* lds_base_uniform, const void* g) {
    __builtin_amdgcn_global_load_lds(
        (const __attribute__((address_space(1))) void*)g,
        (__attribute__((address_space(3))) void*)lds_base_uniform, 16, 0, 0);
}

#define AS_OFF 65536          // As starts after Bs (64 KB); total smem 73728

__global__ __launch_bounds__(256, 2)
void capsule_mfma(const float* __restrict__ x, const _Float16* __restrict__ Wh,
                  const _Float16* __restrict__ Wl, float* __restrict__ out) {
    __shared__ __align__(16) char smem[73728];   // Bs 64K + As 8K; u_lds unions low 66.56K
    _Float16 (*Bs)[2][NDIM][16] = (_Float16 (*)[2][NDIM][16])smem;  // [buf][h/l][n][k']
    float (*u_lds)[520] = (float (*)[520])smem;

    const int tid  = threadIdx.x;
    const int w    = tid >> 6;          // wave 0..3
    const int lane = tid & 63;
    const int ln = lane & 31, q = lane >> 5;
    const int rowBlk = blockIdx.x * 64;
    const int C0 = w * 128;             // wave's column range

    floatx16 acc[2][4];
#pragma unroll
    for (int mf = 0; mf < 2; ++mf)
#pragma unroll
        for (int nt = 0; nt < 4; ++nt)
#pragma unroll
            for (int i = 0; i < 16; ++i) acc[mf][nt][i] = 0.f;

    // ---- A staging assignment: thread -> (row, k-quarter), coalesced ----
    const int srow = tid >> 2;          // 0..63
    const int skq  = tid & 3;           // quarter: 4 floats
    const float* sga = x + (size_t)(rowBlk + srow) * KDIM + skq * 4;
    const int ssw = (srow >> 1) & 3;    // swizzle key
    const int swoff_h = srow * 64 + (((skq >> 1) ^ ssw) * 16) + (skq & 1) * 8;
    const int swoff_l = srow * 64 + ((((skq >> 1) ^ 2) ^ ssw) * 16) + (skq & 1) * 8;

    // ---- A frag read offsets (per mf, per q): pos_h = q^asw, pos_l = (q^2)^asw
    int afr_h[2], afr_l[2];
#pragma unroll
    for (int mf = 0; mf < 2; ++mf) {
        const int ar = mf * 32 + ln;                    // local row 0..63
        const int asw = (ar >> 1) & 3;
        afr_h[mf] = ar * 64 + ((q ^ asw) * 16);
        afr_l[mf] = ar * 64 + (((q ^ 2) ^ asw) * 16);
    }

    // B staging: wave w copies n in [w*128, w*128+128) for h and l (8 x 1KB)
    const int nseg = w * 128;

    // ---- stage kt=0 ----
    {
        const floatx4 v0 = *(const floatx4*)sga;
        half4t h4, l4;
#pragma unroll
        for (int j = 0; j < 4; ++j) {
            h4[j] = (_Float16)v0[j];
            l4[j] = (_Float16)(v0[j] - (float)h4[j]);
        }
        *(half4t*)(smem + AS_OFF + swoff_h) = h4;
        *(half4t*)(smem + AS_OFF + swoff_l) = l4;
    }
#pragma unroll
    for (int i = 0; i < 4; ++i) {
        ld_g2l_16(&Bs[0][0][nseg + i * 32][0], Wh + (size_t)(nseg + i * 32) * 16 + lane * 8);
        ld_g2l_16(&Bs[0][1][nseg + i * 32][0], Wl + (size_t)(nseg + i * 32) * 16 + lane * 8);
    }

#pragma unroll 2
    for (int kt = 0; kt < NKT; ++kt) {
        __syncthreads();               // stage(kt) complete (vm + lgkm drained)
        const int buf = kt & 1;
        floatx4 sv;
        if (kt + 1 < NKT) {            // stage(kt+1): A global load + B async DMA
            sv = *(const floatx4*)(sga + (kt + 1) * 16);
            const size_t g = (size_t)(kt + 1) * (NDIM * 16);
#pragma unroll
            for (int i = 0; i < 4; ++i) {
                ld_g2l_16(&Bs[buf ^ 1][0][nseg + i * 32][0], Wh + g + (size_t)(nseg + i * 32) * 16 + lane * 8);
                ld_g2l_16(&Bs[buf ^ 1][1][nseg + i * 32][0], Wl + g + (size_t)(nseg + i * 32) * 16 + lane * 8);
            }
        }
        // A frags from LDS (swizzled, conflict-free)
        const int abase = AS_OFF + buf * 4096;
        half8 ah[2], al[2];
#pragma unroll
        for (int mf = 0; mf < 2; ++mf) {
            ah[mf] = *(const half8*)(smem + abase + afr_h[mf]);
            al[mf] = *(const half8*)(smem + abase + afr_l[mf]);
        }
#pragma unroll
        for (int nt = 0; nt < 4; ++nt) {
            const half8 bh = *(const half8*)&Bs[buf][0][C0 + nt * 32 + ln][q * 8];
            const half8 bl = *(const half8*)&Bs[buf][1][C0 + nt * 32 + ln][q * 8];
#pragma unroll
            for (int mf = 0; mf < 2; ++mf) {
                acc[mf][nt] = __builtin_amdgcn_mfma_f32_32x32x16_f16(ah[mf], bh, acc[mf][nt], 0, 0, 0);
                acc[mf][nt] = __builtin_amdgcn_mfma_f32_32x32x16_f16(al[mf], bh, acc[mf][nt], 0, 0, 0);
                acc[mf][nt] = __builtin_amdgcn_mfma_f32_32x32x16_f16(ah[mf], bl, acc[mf][nt], 0, 0, 0);
            }
        }
        if (kt + 1 < NKT) {            // A cvt + ds_write into other buffer
            half4t h4, l4;
#pragma unroll
            for (int j = 0; j < 4; ++j) {
                h4[j] = (_Float16)sv[j];
                l4[j] = (_Float16)(sv[j] - (float)h4[j]);
            }
            const int nbase = AS_OFF + (buf ^ 1) * 4096;
            *(half4t*)(smem + nbase + swoff_h) = h4;
            *(half4t*)(smem + nbase + swoff_l) = l4;
        }
    }

    // ---- epilogue: two 32-row phases; acc -> u_lds fp32, then routing ----
    // C/D layout 32x32: col = ln, row = (reg&3) + 8*(reg>>2) + 4*q
    // routing lane map: cap = lane>>2 (bits 2..5), dgrp = lane&3 (bits 0..1)
    // p-loop MUST be unrolled so acc[p] is compile-time (else spill — R6!).
    const int dgrp = lane & 3;
#pragma unroll
    for (int p = 0; p < 2; ++p) {
        __syncthreads();               // previous-phase / K-loop LDS reads done
        {
            const int mf = p;          // all 4 waves write their col slice
#pragma unroll
            for (int nt = 0; nt < 4; ++nt)
#pragma unroll
                for (int reg = 0; reg < 16; ++reg)
                    u_lds[(reg & 3) + 8 * (reg >> 2) + 4 * q][C0 + nt * 32 + ln] = acc[mf][nt][reg];
        }
        __syncthreads();
#pragma unroll 1
        for (int ri = 0; ri < 8; ++ri) {
            const int rl = w * 8 + ri;               // local row 0..31
            const floatx4 ua = *(const floatx4*)&u_lds[rl][lane * 8];
            const floatx4 ub = *(const floatx4*)&u_lds[rl][lane * 8 + 4];
            const float u8[8] = {ua[0], ua[1], ua[2], ua[3],
                                 ub[0], ub[1], ub[2], ub[3]};
            float b_own = 0.f;
            float v[8];
#pragma unroll
            for (int it = 0; it < 3; ++it) {
                float c_own;
                if (it == 0) {
                    c_own = 1.0f / 16.0f;            // softmax of zeros
                } else {
                    const float m = cap_max(b_own);
                    const float e = __expf(b_own - m);
                    const float ssum = cap_sum(e);
                    c_own = e / ssum;
                }
                float s[8];
#pragma unroll
                for (int j = 0; j < 8; ++j) s[j] = c_own * u8[j];
#pragma unroll
                for (int j = 0; j < 8; ++j) s[j] += dpp_mov<ROR4>(s[j]);
#pragma unroll
                for (int j = 0; j < 8; ++j) s[j] += dpp_mov<ROR8>(s[j]);
#pragma unroll
                for (int j = 0; j < 8; ++j) s[j] += swz_xor<16>(s[j]);
#pragma unroll
                for (int j = 0; j < 8; ++j) s[j] += __shfl_xor(s[j], 32);
                float nrm = 0.f;
#pragma unroll
                for (int j = 0; j < 8; ++j) nrm = fmaf(s[j], s[j], nrm);
                nrm = dg_sum(nrm);
                const float scale = nrm / ((1.f + nrm) * (sqrtf(nrm) + EPS_F));
#pragma unroll
                for (int j = 0; j < 8; ++j) v[j] = scale * s[j];
                if (it < 2) {
                    float dot = 0.f;
#pragma unroll
                    for (int j = 0; j < 8; ++j) dot = fmaf(u8[j], v[j], dot);
                    dot = dg_sum(dot);
                    b_own += dot;
                }
            }
            if (lane < 4) {
                float4* o = (float4*)(out + (size_t)(rowBlk + p * 32 + rl) * OUT_DIM
                                      + dgrp * 8);
                o[0] = make_float4(v[0], v[1], v[2], v[3]);
                o[1] = make_float4(v[4], v[5], v[6], v[7]);
            }
        }
    }
}

extern "C" void kernel_launch(void* const* d_in, const int* in_sizes, int n_in,
                              void* d_out, int out_size, void* d_ws, size_t ws_size,
                              hipStream_t stream) {
    const float* x = (const float*)d_in[0];   // [32768, 512]
    const float* W = (const float*)d_in[1];   // [512, 512]
    float* out = (float*)d_out;               // [32768, 32]
    _Float16* Wh = (_Float16*)d_ws;           // [32][512][16] f16 tiled
    _Float16* Wl = Wh + (size_t)NDIM * KDIM;

    prep_w<<<dim3(16, 16), dim3(32, 8), 0, stream>>>(W, Wh, Wl);
    capsule_mfma<<<dim3(BATCH / 64), dim3(256), 0, stream>>>(x, Wh, Wl, out);
}

// Round 10
// 156.632 us; speedup vs baseline: 1.0109x; 1.0109x over previous
//
#include <hip/hip_runtime.h>
#include <math.h>

// CapsuleLayer: u = x@W via split-precision f16 MFMA (xh@Wh + xl@Wh + xh@Wl),
// 32x32x16. R10: BARRIER-FREE K-loop (break the m97 plateau, R9 post-mortem):
//  - B frags: direct global->VGPR loads from tiled Wh/Wl (1KB coalesced),
//    ping-pong 2 register sets prefetched one nt ahead; loads stay in flight
//    across kt (no vmcnt(0) drain anywhere in the K-loop).
//  - A: cooperative LDS staging in 8-kt superblocks (dbuf 2x32KB), barrier
//    only 4x per kernel. Swizzled f16 hi/lo chunks -> conflict-free b128
//    frag reads (8-lane groups cover all 32 banks).
// Proven invariants: never runtime-index acc[] (R6 spill); lane-bit-5 cross
// only via bpermute (R5); C/D layout row=(reg&3)+8*(reg>>2)+4*q, col=ln.
//
// x: [32768,512] fp32  W: [512,512] fp32  v: [32768,32] fp32
// prep_w: W[k][n] -> Wh/Wl tiled [kt][n][k%16] f16 in d_ws (1 MB).
// Main: block = 256 thr (4 waves), tile 64 rows x 512 cols, grid 512
// (2 blocks/CU: LDS 66.56KB, VGPR<=256 via __launch_bounds__(256,2)).
// Wave w: all 64 rows (2 m-frags) x cols w*128..+127 (4 n-tiles).

#define BATCH   32768
#define KDIM    512
#define NDIM    512
#define OUT_DIM 32
#define EPS_F   1e-8f
#define NKT     32            // K tiles of 16
#define KPS     8             // kt per superblock
#define NSB     4             // superblocks

typedef _Float16 half8  __attribute__((ext_vector_type(8)));
typedef _Float16 half4t __attribute__((ext_vector_type(4)));
typedef float   floatx4 __attribute__((ext_vector_type(4)));
typedef float  floatx16 __attribute__((ext_vector_type(16)));

// ---- cross-lane helpers (R7, proven) ----
template <int CTRL>
__device__ __forceinline__ float dpp_mov(float x) {
    return __int_as_float(__builtin_amdgcn_mov_dpp(__float_as_int(x), CTRL, 0xF, 0xF, true));
}
template <int XMASK>   // XMASK <= 31: ds_swizzle BitMode xor (within 32-lane group)
__device__ __forceinline__ float swz_xor(float x) {
    return __int_as_float(__builtin_amdgcn_ds_swizzle(__float_as_int(x), (XMASK << 10) | 31));
}
#define ROR4  0x124
#define ROR8  0x128
#define QXOR1 0xB1
#define QXOR2 0x4E

__device__ __forceinline__ float cap_sum(float x) {
    x += dpp_mov<ROR4>(x);
    x += dpp_mov<ROR8>(x);
    x += swz_xor<16>(x);
    x += __shfl_xor(x, 32);          // lane bit 5: bpermute only
    return x;
}
__device__ __forceinline__ float cap_max(float x) {
    x = fmaxf(x, dpp_mov<ROR4>(x));
    x = fmaxf(x, dpp_mov<ROR8>(x));
    x = fmaxf(x, swz_xor<16>(x));
    x = fmaxf(x, __shfl_xor(x, 32));
    return x;
}
__device__ __forceinline__ float dg_sum(float x) {
    x += dpp_mov<QXOR1>(x);
    x += dpp_mov<QXOR2>(x);
    return x;
}

// ---- prep: W[k][n] fp32 -> Wh/Wl [kt][n][k%16] f16 hi/lo split ----
__global__ void prep_w(const float* __restrict__ W, _Float16* __restrict__ Wh,
                       _Float16* __restrict__ Wl) {
    __shared__ float tile[32][33];
    const int tx = threadIdx.x, ty = threadIdx.y;      // block (32, 8)
    const int n0 = blockIdx.x * 32, k0 = blockIdx.y * 32;
#pragma unroll
    for (int i = 0; i < 4; ++i)
        tile[ty + 8 * i][tx] = W[(size_t)(k0 + ty + 8 * i) * NDIM + n0 + tx];
    __syncthreads();
#pragma unroll
    for (int i = 0; i < 4; ++i) {
        const int k = k0 + tx, n = n0 + ty + 8 * i;
        const float v = tile[tx][ty + 8 * i];          // = W[k][n]
        const _Float16 h = (_Float16)v;
        const _Float16 l = (_Float16)(v - (float)h);
        const size_t off = (size_t)(k >> 4) * (NDIM * 16) + (size_t)n * 16 + (k & 15);
        Wh[off] = h;
        Wl[off] = l;
    }
}

__global__ __launch_bounds__(256, 2)
void capsule_mfma(const float* __restrict__ x, const _Float16* __restrict__ Wh,
                  const _Float16* __restrict__ Wl, float* __restrict__ out) {
    // As[buf(2)][kt'(8)][row 64][64B] = 64 KB, unioned with u_lds[32][520] (66.56 KB)
    __shared__ __align__(16) char smem[66560];
    float (*u_lds)[520] = (float (*)[520])smem;

    const int tid  = threadIdx.x;
    const int w    = tid >> 6;          // wave 0..3
    const int lane = tid & 63;
    const int ln = lane & 31, q = lane >> 5;
    const int rowBlk = blockIdx.x * 64;
    const int C0 = w * 128;

    floatx16 acc[2][4];
#pragma unroll
    for (int mf = 0; mf < 2; ++mf)
#pragma unroll
        for (int nt = 0; nt < 4; ++nt)
#pragma unroll
            for (int i = 0; i < 16; ++i) acc[mf][nt][i] = 0.f;

    // ---- A staging mapping: thread -> (row srow0+8i, kt' skt, quarter skq) ----
    const int srow0 = tid >> 5;          // 0..7
    const int sf    = tid & 31;
    const int skt   = sf >> 2;           // 0..7
    const int skq   = sf & 3;
    const float* aga = x + (size_t)(rowBlk + srow0) * KDIM + skt * 16 + skq * 4;
    const int ssw = (srow0 >> 1) & 3;    // i-invariant ((+8i)>>1 adds 4, &3 unchanged)
    const int woffh = skt * 4096 + srow0 * 64 + (((skq >> 1) ^ ssw) * 16) + (skq & 1) * 8;
    // l-chunk offset = woffh ^ 32

    // ---- A frag read offsets: ar = mf*32+ln; hoff1 = hoff0 + 2048; loff = hoff^32
    const int hoff0 = ln * 64 + ((q ^ ((ln >> 1) & 3)) * 16);

    // ---- B lane offset (halfs): frag (kt,nt) at Wh + kt*8192 + nt*512 + boff
    const int boff = (C0 + ln) * 16 + q * 8;

    // ---- prologue: stage slice 0 -> buf0; load B(0,0) ----
    {
        floatx4 s0[8];
#pragma unroll
        for (int i = 0; i < 8; ++i)
            s0[i] = *(const floatx4*)(aga + (size_t)(8 * i) * KDIM);
#pragma unroll
        for (int i = 0; i < 8; ++i) {
            half4t h4, l4;
#pragma unroll
            for (int j = 0; j < 4; ++j) {
                h4[j] = (_Float16)s0[i][j];
                l4[j] = (_Float16)(s0[i][j] - (float)h4[j]);
            }
            *(half4t*)(smem + woffh + i * 512)        = h4;
            *(half4t*)(smem + (woffh ^ 32) + i * 512) = l4;
        }
    }
    half8 bh[2], bl[2];
    bh[0] = *(const half8*)(Wh + boff);
    bl[0] = *(const half8*)(Wl + boff);

#define COMPUTE_KK(kk)                                                          \
    {                                                                           \
        const int kt = s * KPS + (kk);                                          \
        const char* ab = smem + abuf + (kk) * 4096;                             \
        const half8 ah0 = *(const half8*)(ab + hoff0);                          \
        const half8 al0 = *(const half8*)(ab + (hoff0 ^ 32));                   \
        const half8 ah1 = *(const half8*)(ab + hoff0 + 2048);                   \
        const half8 al1 = *(const half8*)(ab + ((hoff0 + 2048) ^ 32));          \
        _Pragma("unroll")                                                       \
        for (int nt = 0; nt < 4; ++nt) {                                        \
            const int cu = nt & 1, nx = cu ^ 1;                                 \
            const int kn = (nt < 3) ? kt : ((kt + 1 < NKT) ? kt + 1 : kt);      \
            const int nn = (nt < 3) ? nt + 1 : 0;                               \
            bh[nx] = *(const half8*)(Wh + (size_t)kn * 8192 + nn * 512 + boff); \
            bl[nx] = *(const half8*)(Wl + (size_t)kn * 8192 + nn * 512 + boff); \
            acc[0][nt] = __builtin_amdgcn_mfma_f32_32x32x16_f16(ah0, bh[cu], acc[0][nt], 0, 0, 0); \
            acc[0][nt] = __builtin_amdgcn_mfma_f32_32x32x16_f16(al0, bh[cu], acc[0][nt], 0, 0, 0); \
            acc[0][nt] = __builtin_amdgcn_mfma_f32_32x32x16_f16(ah0, bl[cu], acc[0][nt], 0, 0, 0); \
            acc[1][nt] = __builtin_amdgcn_mfma_f32_32x32x16_f16(ah1, bh[cu], acc[1][nt], 0, 0, 0); \
            acc[1][nt] = __builtin_amdgcn_mfma_f32_32x32x16_f16(al1, bh[cu], acc[1][nt], 0, 0, 0); \
            acc[1][nt] = __builtin_amdgcn_mfma_f32_32x32x16_f16(ah1, bl[cu], acc[1][nt], 0, 0, 0); \
        }                                                                       \
    }

#define STAGE_HALF(h0)                                                          \
    {                                                                           \
        half4t h4, l4;                                                          \
        _Pragma("unroll")                                                       \
        for (int i = 0; i < 4; ++i) {                                           \
            _Pragma("unroll")                                                   \
            for (int j = 0; j < 4; ++j) {                                       \
                h4[j] = (_Float16)sv[i][j];                                     \
                l4[j] = (_Float16)(sv[i][j] - (float)h4[j]);                    \
            }                                                                   \
            *(half4t*)(smem + nbuf + woffh + ((h0) + i) * 512)        = h4;     \
            *(half4t*)(smem + nbuf + ((woffh ^ 32)) + ((h0) + i) * 512) = l4;   \
        }                                                                       \
    }

#pragma unroll 1
    for (int s = 0; s < NSB; ++s) {
        __syncthreads();               // stage(slice s) visible; buf^1 readers done
        const int abuf = (s & 1) * 32768;
        const int nbuf = abuf ^ 32768;
        floatx4 sv[4];
        if (s + 1 < NSB) {             // load half 0 of slice s+1 (rows +0..+24)
#pragma unroll
            for (int i = 0; i < 4; ++i)
                sv[i] = *(const floatx4*)(aga + (size_t)(s + 1) * 128 + (size_t)(8 * i) * KDIM);
        }
        COMPUTE_KK(0)
        COMPUTE_KK(1)
        if (s + 1 < NSB) STAGE_HALF(0)
        if (s + 1 < NSB) {             // load half 1 (rows +32..+56)
#pragma unroll
            for (int i = 0; i < 4; ++i)
                sv[i] = *(const floatx4*)(aga + (size_t)(s + 1) * 128 + (size_t)(8 * (i + 4)) * KDIM);
        }
        COMPUTE_KK(2)
        COMPUTE_KK(3)
        COMPUTE_KK(4)
        COMPUTE_KK(5)
        if (s + 1 < NSB) STAGE_HALF(4)
        COMPUTE_KK(6)
        COMPUTE_KK(7)
    }

    // ---- epilogue: two 32-row phases; acc -> u_lds fp32, then routing ----
    // C/D layout 32x32: col = ln, row = (reg&3) + 8*(reg>>2) + 4*q
    const int dgrp = lane & 3;
#pragma unroll
    for (int p = 0; p < 2; ++p) {
        __syncthreads();               // K-loop / previous-phase LDS reads done
        {
            const int mf = p;          // compile-time (p unrolled) — R6 rule
#pragma unroll
            for (int nt = 0; nt < 4; ++nt)
#pragma unroll
                for (int reg = 0; reg < 16; ++reg)
                    u_lds[(reg & 3) + 8 * (reg >> 2) + 4 * q][C0 + nt * 32 + ln] = acc[mf][nt][reg];
        }
        __syncthreads();
#pragma unroll 1
        for (int ri = 0; ri < 8; ++ri) {
            const int rl = w * 8 + ri;               // local row 0..31
            const floatx4 ua = *(const floatx4*)&u_lds[rl][lane * 8];
            const floatx4 ub = *(const floatx4*)&u_lds[rl][lane * 8 + 4];
            const float u8[8] = {ua[0], ua[1], ua[2], ua[3],
                                 ub[0], ub[1], ub[2], ub[3]};
            float b_own = 0.f;
            float v[8];
#pragma unroll
            for (int it = 0; it < 3; ++it) {
                float c_own;
                if (it == 0) {
                    c_own = 1.0f / 16.0f;            // softmax of zeros
                } else {
                    const float m = cap_max(b_own);
                    const float e = __expf(b_own - m);
                    const float ssum = cap_sum(e);
                    c_own = e / ssum;
                }
                float s8[8];
#pragma unroll
                for (int j = 0; j < 8; ++j) s8[j] = c_own * u8[j];
#pragma unroll
                for (int j = 0; j < 8; ++j) s8[j] += dpp_mov<ROR4>(s8[j]);
#pragma unroll
                for (int j = 0; j < 8; ++j) s8[j] += dpp_mov<ROR8>(s8[j]);
#pragma unroll
                for (int j = 0; j < 8; ++j) s8[j] += swz_xor<16>(s8[j]);
#pragma unroll
                for (int j = 0; j < 8; ++j) s8[j] += __shfl_xor(s8[j], 32);
                float nrm = 0.f;
#pragma unroll
                for (int j = 0; j < 8; ++j) nrm = fmaf(s8[j], s8[j], nrm);
                nrm = dg_sum(nrm);
                const float scale = nrm / ((1.f + nrm) * (sqrtf(nrm) + EPS_F));
#pragma unroll
                for (int j = 0; j < 8; ++j) v[j] = scale * s8[j];
                if (it < 2) {
                    float dot = 0.f;
#pragma unroll
                    for (int j = 0; j < 8; ++j) dot = fmaf(u8[j], v[j], dot);
                    dot = dg_sum(dot);
                    b_own += dot;
                }
            }
            if (lane < 4) {
                float4* o = (float4*)(out + (size_t)(rowBlk + p * 32 + rl) * OUT_DIM
                                      + dgrp * 8);
                o[0] = make_float4(v[0], v[1], v[2], v[3]);
                o[1] = make_float4(v[4], v[5], v[6], v[7]);
            }
        }
    }
}

extern "C" void kernel_launch(void* const* d_in, const int* in_sizes, int n_in,
                              void* d_out, int out_size, void* d_ws, size_t ws_size,
                              hipStream_t stream) {
    const float* x = (const float*)d_in[0];   // [32768, 512]
    const float* W = (const float*)d_in[1];   // [512, 512]
    float* out = (float*)d_out;               // [32768, 32]
    _Float16* Wh = (_Float16*)d_ws;           // [32][512][16] f16 tiled
    _Float16* Wl = Wh + (size_t)NDIM * KDIM;

    prep_w<<<dim3(16, 16), dim3(32, 8), 0, stream>>>(W, Wh, Wl);
    capsule_mfma<<<dim3(BATCH / 64), dim3(256), 0, stream>>>(x, Wh, Wl, out);
}